// Round 2
// baseline (510.470 us; speedup 1.0000x reference)
//
#include <hip/hip_runtime.h>
#include <hip/hip_bf16.h>
#include <stdint.h>

// Problem constants (fixed by setup_inputs)
#define B_SZ  8
#define N_Q   8192
#define M_PT  2048
#define C1    128
#define C2    256
#define CIN   384      // C1 + C2
#define H_OUT 256
#define R_TOT 65536    // B_SZ * N_Q

typedef __bf16 bf16x8 __attribute__((ext_vector_type(8)));
typedef __bf16 bf16x4 __attribute__((ext_vector_type(4)));
typedef float  f32x4  __attribute__((ext_vector_type(4)));

// Async global->LDS, 16B per lane. LDS dest is wave-uniform base + lane*16.
__device__ __forceinline__ void async_copy16(const void* g, void* l) {
    __builtin_amdgcn_global_load_lds(
        (const __attribute__((address_space(1))) unsigned int*)g,
        (__attribute__((address_space(3))) unsigned int*)l,
        16, 0, 0);
}

// ---------------------------------------------------------------------------
// K1: convert folds (p1/p2 -> bf16, W1 split, W2) + per-batch x-sort of xyz2.
// Sort blocks FIRST (blockIdx 0..63) so their ~5 us runs under the ~12 us of
// streaming converts on the other CUs.  Sort = O(M^2) rank-by-count with
// (x, idx) lexicographic tie-break -> sorted[b][rank] = (x,y,z,orig_idx).
// ---------------------------------------------------------------------------
__global__ __launch_bounds__(256) void convert_sort(
    const float* __restrict__ xyz2, const float* __restrict__ p1,
    const float* __restrict__ p2,   const float* __restrict__ W1,
    const float* __restrict__ W2,
    __bf16* __restrict__ p1b,  __bf16* __restrict__ p2b,
    __bf16* __restrict__ wb1a, __bf16* __restrict__ wb1b,
    __bf16* __restrict__ wb2,  float4* __restrict__ sorted) {
    const int tid = threadIdx.x;

    if (blockIdx.x < 64) {   // ---- sort blocks: (b, chunk-of-256-points)
        __shared__ __attribute__((aligned(16))) float xs[M_PT];
        const int b  = blockIdx.x >> 3;
        const int ch = blockIdx.x & 7;
        const float* x2 = xyz2 + (size_t)b * M_PT * 3;
#pragma unroll
        for (int j = tid; j < M_PT; j += 256) xs[j] = x2[j * 3];
        __syncthreads();
        const int   i  = ch * 256 + tid;
        const float xi = xs[i];
        const float yi = x2[i * 3 + 1], zi = x2[i * 3 + 2];
        int rank = 0;
#pragma unroll 4
        for (int j = 0; j < M_PT; j += 4) {
            const float4 xv = *(const float4*)&xs[j];
            rank += (xv.x < xi || (xv.x == xi && (j + 0) < i)) ? 1 : 0;
            rank += (xv.y < xi || (xv.y == xi && (j + 1) < i)) ? 1 : 0;
            rank += (xv.z < xi || (xv.z == xi && (j + 2) < i)) ? 1 : 0;
            rank += (xv.w < xi || (xv.w == xi && (j + 3) < i)) ? 1 : 0;
        }
        sorted[(size_t)b * M_PT + rank] =
            make_float4(xi, yi, zi, __int_as_float(i));
        return;
    }

    // ---- convert blocks: cb in [0, 2048)
    const int cb  = blockIdx.x - 64;
    const int gid = cb * 256 + tid;           // 0..524287

    // p2 -> bf16 (4,194,304 elems = 524288 threads x 8)
    {
        const float4* src = (const float4*)p2 + (size_t)gid * 2;
        float4 a = src[0], bb = src[1];
        bf16x8 o;
        o[0]=(__bf16)a.x; o[1]=(__bf16)a.y; o[2]=(__bf16)a.z; o[3]=(__bf16)a.w;
        o[4]=(__bf16)bb.x; o[5]=(__bf16)bb.y; o[6]=(__bf16)bb.z; o[7]=(__bf16)bb.w;
        *(bf16x8*)(p2b + (size_t)gid * 8) = o;
    }
    // W1 split-convert (98304 elems) / W2 convert (65536 elems)
    if (cb < 384) {
        const int e = gid;                       // 0..98303
        const int o = e / 384, k = e - o * 384;
        __bf16 v = (__bf16)W1[e];
        if (k < C1) wb1a[o * C1 + k] = v;
        else        wb1b[o * C2 + (k - C1)] = v;
    } else if (cb < 640) {
        const int e = gid - 98304;               // 0..65535
        wb2[e] = (__bf16)W2[e];
    }
    // p1 -> bf16 (8,388,608 elems = 524288 threads x 16)
    {
        const float4* src = (const float4*)p1 + (size_t)gid * 4;
        float4 a = src[0], bb = src[1], cc = src[2], dd = src[3];
        bf16x8 o0, o1;
        o0[0]=(__bf16)a.x; o0[1]=(__bf16)a.y; o0[2]=(__bf16)a.z; o0[3]=(__bf16)a.w;
        o0[4]=(__bf16)bb.x; o0[5]=(__bf16)bb.y; o0[6]=(__bf16)bb.z; o0[7]=(__bf16)bb.w;
        o1[0]=(__bf16)cc.x; o1[1]=(__bf16)cc.y; o1[2]=(__bf16)cc.z; o1[3]=(__bf16)cc.w;
        o1[4]=(__bf16)dd.x; o1[5]=(__bf16)dd.y; o1[6]=(__bf16)dd.z; o1[7]=(__bf16)dd.w;
        *(bf16x8*)(p1b + (size_t)gid * 16)     = o0;
        *(bf16x8*)(p1b + (size_t)gid * 16 + 8) = o1;
    }
}

// ---------------------------------------------------------------------------
// K2: sorted-sweep KNN.  2 threads per query (even=left, odd=right sweep);
// 256 threads = 128 queries of ONE batch; grid = 8 batches x 64 blocks = 512.
// sorted batch array staged in LDS (32 KB).  Distance uses the SAME expansion
// form as the passing round-0 kernel (d' = |p|^2 - 2 q.p via fmaf chain;
// |q|^2 added only in the weights) so selection values bitwise-match it.
// Each lane sweeps monotonically away from the query's x-position tracking
// (d', orig-idx) top-3 with (value, index) lexicographic order (matches
// top_k's ascending-index tie rule); every 8 points the pair exchanges v2
// and a lane stops when its (dx)^2 exceeds merged-v2 + |q|^2 + 1e-3 guard
// (covers the <=4e-5 fp error of the expansion vs the geometric bound).
// ---------------------------------------------------------------------------
__global__ __launch_bounds__(256, 4) void knn_sweep(
    const float* __restrict__ xyz1, const float4* __restrict__ sorted,
    float4* __restrict__ w4, int4* __restrict__ gidx4) {
    __shared__ __attribute__((aligned(16))) float4 pts[M_PT];   // 32 KB
    const int tid  = threadIdx.x;
    const int b    = blockIdx.x >> 6;        // 64 blocks per batch
    const int qb   = blockIdx.x & 63;        // 128 queries per block
    const int wave = tid >> 6, lane = tid & 63;

    {   // stage sorted[b] (2048 float4) into LDS, async 16B per lane
        const float4* src = sorted + (size_t)b * M_PT;
#pragma unroll
        for (int j = 0; j < 8; ++j)
            async_copy16(src + j * 256 + wave * 64 + lane,
                         (char*)pts + ((j * 256 + wave * 64) << 4));
    }
    __syncthreads();

    const int   side = tid & 1;                      // 0 = left, 1 = right
    const int   qid  = b * N_Q + qb * 128 + (tid >> 1);
    const float* qp  = xyz1 + (size_t)qid * 3;
    const float qx = qp[0], qy = qp[1], qz = qp[2];
    const float n1q = fmaf(qx, qx, fmaf(qy, qy, qz * qz));

    // lower_bound on pts[].x: after 11 steps the range is <=1; the sweep
    // start (left from lo-1, right from lo) still covers all points.
    int lo = 0, hi = M_PT;
#pragma unroll
    for (int s = 0; s < 11; ++s) {
        const int mid = (lo + hi) >> 1;
        const bool lt = pts[mid].x < qx;
        lo = lt ? mid + 1 : lo;
        hi = lt ? hi : mid;
    }

    float v0 = 3.4e38f, v1 = 3.4e38f, v2 = 3.4e38f;
    int   i0 = 0, i1 = 0, i2 = 0;
    int   ptr  = side ? lo : lo - 1;
    const int step = side ? 1 : -1;
    bool done = false;

    // hard cap: 272*8 > 2048, so even if the early-out never fires every
    // in-bounds point has been scanned and further iterations are no-ops.
    for (int it = 0; it < 272; ++it) {
        if (!__any(!done)) break;
        float lastb = 3.4e38f;
#pragma unroll
        for (int k = 0; k < 8; ++k) {
            const int  pc  = ptr & (M_PT - 1);
            const bool inb = (unsigned)ptr < (unsigned)M_PT;
            const float4 p = pts[pc];
            const float dx = qx - p.x;
            const float bx = dx * dx;
            const float pw = fmaf(p.x, p.x, fmaf(p.y, p.y, p.z * p.z));
            float d = fmaf(-2.f * p.x, qx,
                      fmaf(-2.f * p.y, qy, fmaf(-2.f * p.z, qz, pw)));
            d = inb ? d : 3.4e38f;
            const int j = inb ? __float_as_int(p.w) : 0x7fffffff;
            // branchless sorted-3 insert, (value, index) lexicographic
            const bool c0 = d < v0 || (d == v0 && j < i0);
            const bool c1 = d < v1 || (d == v1 && j < i1);
            const bool c2 = d < v2 || (d == v2 && j < i2);
            const float n0 = fminf(d, v0);
            const float n1 = __builtin_amdgcn_fmed3f(d, v0, v1);
            const float n2 = __builtin_amdgcn_fmed3f(d, v1, v2);
            i2 = c1 ? i1 : (c2 ? j : i2);
            i1 = c0 ? i0 : (c1 ? j : i1);
            i0 = c0 ? j  : i0;
            v0 = n0; v1 = n1; v2 = n2;
            if (k == 7) lastb = inb ? bx : 3.4e38f;
            ptr += step;
        }
        const float v2m = fminf(v2, __shfl_xor(v2, 1));
        // remaining points on this side: true d >= dx^2 >= lastb, so their
        // d' >= lastb - n1q - fp_err; stop when lastb >= v2m + n1q + 1e-3.
        // clamp keeps the test true when both sides are exhausted (3.4e38).
        const float thr = fminf(v2m + n1q + 1e-3f, 3.0e38f);
        done = done || (lastb >= thr);
    }

    // merge partner's triple (sides are disjoint point sets)
    const float m0 = __shfl_xor(v0, 1), m1 = __shfl_xor(v1, 1),
                m2 = __shfl_xor(v2, 1);
    const int   j0 = __shfl_xor(i0, 1), j1 = __shfl_xor(i1, 1),
                j2 = __shfl_xor(i2, 1);
#pragma unroll
    for (int t = 0; t < 3; ++t) {
        const float d = (t == 0) ? m0 : (t == 1) ? m1 : m2;
        const int   j = (t == 0) ? j0 : (t == 1) ? j1 : j2;
        const bool c0 = d < v0 || (d == v0 && j < i0);
        const bool c1 = d < v1 || (d == v1 && j < i1);
        const bool c2 = d < v2 || (d == v2 && j < i2);
        const float n0 = fminf(d, v0);
        const float n1 = __builtin_amdgcn_fmed3f(d, v0, v1);
        const float n2 = __builtin_amdgcn_fmed3f(d, v1, v2);
        i2 = c1 ? i1 : (c2 ? j : i2);
        i1 = c0 ? i0 : (c1 ? j : i1);
        i0 = c0 ? j  : i0;
        v0 = n0; v1 = n1; v2 = n2;
    }

    if (side == 0) {   // weights: identical formula to round-0 (passed)
        const float r0 = 1.f / ((v0 + n1q) + 1e-8f);
        const float r1 = 1.f / ((v1 + n1q) + 1e-8f);
        const float r2 = 1.f / ((v2 + n1q) + 1e-8f);
        const float rs = 1.f / (r0 + r1 + r2);
        w4[qid]    = make_float4(r0 * rs, r1 * rs, r2 * rs, 0.f);
        gidx4[qid] = make_int4(i0, i1, i2, 0);
    }
}

// ---------------------------------------------------------------------------
// bf16 MFMA GEMM (m97 structure), optional fused BN-stats partials.
// C stride is H_OUT=256 for all uses (Z, y2).  grid = (rows/128)*2.
// ---------------------------------------------------------------------------
template <int K, bool STATS>
__global__ __launch_bounds__(256, 2) void gemm_bt(const __bf16* __restrict__ A,
                                                  const __bf16* __restrict__ Bw,
                                                  __bf16* __restrict__ Cout,
                                                  float* __restrict__ partS,
                                                  float* __restrict__ partQ) {
    __shared__ __attribute__((aligned(16))) __bf16 As[128 * 32];
    __shared__ __attribute__((aligned(16))) __bf16 Bs[128 * 32];
    const int tid  = threadIdx.x;
    const int wave = tid >> 6, lane = tid & 63;
    const int wm = wave >> 1, wn = wave & 1;
    const int quad = lane >> 4, r16 = lane & 15;
    const int bx = blockIdx.x & 1, by = blockIdx.x >> 1;
    const int l4 = lane >> 2, lk = (lane & 3) * 8;

    f32x4 acc[4][4] = {};

    const __bf16* gA = A  + (size_t)(by * 128 + wave * 32 + l4) * K + lk;
    const __bf16* gB = Bw + (size_t)(bx * 128 + wave * 32 + l4) * K + lk;
    char* lA = (char*)As + wave * 2048;
    char* lB = (char*)Bs + wave * 2048;

    for (int k0 = 0; k0 < K; k0 += 32) {
        async_copy16(gA + k0,                  lA);
        async_copy16(gA + k0 + (size_t)16 * K, lA + 1024);
        async_copy16(gB + k0,                  lB);
        async_copy16(gB + k0 + (size_t)16 * K, lB + 1024);
        __syncthreads();

        bf16x8 af[4], bf[4];
#pragma unroll
        for (int t = 0; t < 4; ++t)
            af[t] = *(const bf16x8*)(As + (wm * 64 + t * 16 + r16) * 32 + quad * 8);
#pragma unroll
        for (int u = 0; u < 4; ++u)
            bf[u] = *(const bf16x8*)(Bs + (wn * 64 + u * 16 + r16) * 32 + quad * 8);
#pragma unroll
        for (int t = 0; t < 4; ++t)
#pragma unroll
            for (int u = 0; u < 4; ++u)
                acc[t][u] = __builtin_amdgcn_mfma_f32_16x16x32_bf16(af[t], bf[u], acc[t][u], 0, 0, 0);
        __syncthreads();
    }

    // C/D layout col=lane&15, row=(lane>>4)*4+reg [m89-verified]
#pragma unroll
    for (int t = 0; t < 4; ++t) {
#pragma unroll
        for (int u = 0; u < 4; ++u) {
            const int col = bx * 128 + wn * 64 + u * 16 + r16;
#pragma unroll
            for (int r = 0; r < 4; ++r) {
                const int row = by * 128 + wm * 64 + t * 16 + quad * 4 + r;
                Cout[(size_t)row * H_OUT + col] = (__bf16)acc[t][u][r];
            }
        }
    }

    if constexpr (STATS) {
        float* redS = (float*)As;          // [col(128)][slot(8)]
        float* redQ = ((float*)As) + 1024;
        const int slot = wm * 4 + quad;
#pragma unroll
        for (int u = 0; u < 4; ++u) {
            float s = 0.f, qq = 0.f;
#pragma unroll
            for (int t = 0; t < 4; ++t)
#pragma unroll
                for (int r = 0; r < 4; ++r) { float v = acc[t][u][r]; s += v; qq = fmaf(v, v, qq); }
            const int col = wn * 64 + u * 16 + r16;
            redS[col * 8 + slot] = s;
            redQ[col * 8 + slot] = qq;
        }
        __syncthreads();
        if (tid < 128) {
            float s = 0.f, qq = 0.f;
#pragma unroll
            for (int k = 0; k < 8; ++k) { s += redS[tid * 8 + k]; qq += redQ[tid * 8 + k]; }
            partS[(size_t)blockIdx.x * 128 + tid] = s;
            partQ[(size_t)blockIdx.x * 128 + tid] = qq;
        }
    }
}

// ---------------------------------------------------------------------------
// GEMM-A (K=128) + fused interpolation epilogue + BN-stats:
//   y1 = p1b @ wb1a^T + sum_k w_k * Z[idx_k]      (linearity of interp)
// Z rows are L2-resident (8.4 MB); gathers are 16-lane-contiguous 2B loads.
// grid = 512*2 = 1024 blocks of 256.  (idx/w come directly from knn_sweep.)
// ---------------------------------------------------------------------------
__global__ __launch_bounds__(256, 2) void gemm_a_int(
    const __bf16* __restrict__ A,  const __bf16* __restrict__ Bw,
    const __bf16* __restrict__ zb, const int4* __restrict__ gidx4,
    const float4* __restrict__ w4, __bf16* __restrict__ Cout,
    float* __restrict__ partS, float* __restrict__ partQ) {
    constexpr int K = C1;   // 128
    __shared__ __attribute__((aligned(16))) __bf16 As[128 * 32];
    __shared__ __attribute__((aligned(16))) __bf16 Bs[128 * 32];
    const int tid  = threadIdx.x;
    const int wave = tid >> 6, lane = tid & 63;
    const int wm = wave >> 1, wn = wave & 1;
    const int quad = lane >> 4, r16 = lane & 15;
    const int bx = blockIdx.x & 1, by = blockIdx.x >> 1;
    const int l4 = lane >> 2, lk = (lane & 3) * 8;

    f32x4 acc[4][4] = {};

    const __bf16* gA = A  + (size_t)(by * 128 + wave * 32 + l4) * K + lk;
    const __bf16* gB = Bw + (size_t)(bx * 128 + wave * 32 + l4) * K + lk;
    char* lA = (char*)As + wave * 2048;
    char* lB = (char*)Bs + wave * 2048;

    for (int k0 = 0; k0 < K; k0 += 32) {
        async_copy16(gA + k0,                  lA);
        async_copy16(gA + k0 + (size_t)16 * K, lA + 1024);
        async_copy16(gB + k0,                  lB);
        async_copy16(gB + k0 + (size_t)16 * K, lB + 1024);
        __syncthreads();

        bf16x8 af[4], bf[4];
#pragma unroll
        for (int t = 0; t < 4; ++t)
            af[t] = *(const bf16x8*)(As + (wm * 64 + t * 16 + r16) * 32 + quad * 8);
#pragma unroll
        for (int u = 0; u < 4; ++u)
            bf[u] = *(const bf16x8*)(Bs + (wn * 64 + u * 16 + r16) * 32 + quad * 8);
#pragma unroll
        for (int t = 0; t < 4; ++t)
#pragma unroll
            for (int u = 0; u < 4; ++u)
                acc[t][u] = __builtin_amdgcn_mfma_f32_16x16x32_bf16(af[t], bf[u], acc[t][u], 0, 0, 0);
        __syncthreads();
    }

    // stage per-row (idx0..2, w0..2) into As (4 KB of the free 8 KB)
    if (tid < 128) {
        const int q = by * 128 + tid;
        ((int4*)As)[tid * 2]       = gidx4[q];
        ((float4*)As)[tid * 2 + 1] = w4[q];
    }
    __syncthreads();

    // add interpolated Z rows into the accumulators
    const int bbase = (by >> 6) * M_PT;   // 64 row-blocks per batch
#pragma unroll
    for (int t = 0; t < 4; ++t) {
#pragma unroll
        for (int r = 0; r < 4; ++r) {
            const int rl = wm * 64 + t * 16 + quad * 4 + r;   // row-in-block
            const int4   ii = ((const int4*)As)[rl * 2];      // broadcast read
            const float4 ww = ((const float4*)As)[rl * 2 + 1];
            const __bf16* z0 = zb + (size_t)(bbase + ii.x) * H_OUT;
            const __bf16* z1 = zb + (size_t)(bbase + ii.y) * H_OUT;
            const __bf16* z2 = zb + (size_t)(bbase + ii.z) * H_OUT;
#pragma unroll
            for (int u = 0; u < 4; ++u) {
                const int col = bx * 128 + wn * 64 + u * 16 + r16;
                acc[t][u][r] += ww.x * (float)z0[col] + ww.y * (float)z1[col]
                              + ww.z * (float)z2[col];
            }
        }
    }

    // C store (bf16 y1)
#pragma unroll
    for (int t = 0; t < 4; ++t) {
#pragma unroll
        for (int u = 0; u < 4; ++u) {
            const int col = bx * 128 + wn * 64 + u * 16 + r16;
#pragma unroll
            for (int r = 0; r < 4; ++r) {
                const int row = by * 128 + wm * 64 + t * 16 + quad * 4 + r;
                Cout[(size_t)row * H_OUT + col] = (__bf16)acc[t][u][r];
            }
        }
    }

    __syncthreads();   // idx/w reads done before stats overwrite As
    float* redS = (float*)As;
    float* redQ = ((float*)As) + 1024;
    const int slot = wm * 4 + quad;
#pragma unroll
    for (int u = 0; u < 4; ++u) {
        float s = 0.f, qq = 0.f;
#pragma unroll
        for (int t = 0; t < 4; ++t)
#pragma unroll
            for (int r = 0; r < 4; ++r) { float v = acc[t][u][r]; s += v; qq = fmaf(v, v, qq); }
        const int col = wn * 64 + u * 16 + r16;
        redS[col * 8 + slot] = s;
        redQ[col * 8 + slot] = qq;
    }
    __syncthreads();
    if (tid < 128) {
        float s = 0.f, qq = 0.f;
#pragma unroll
        for (int k = 0; k < 8; ++k) { s += redS[tid * 8 + k]; qq += redQ[tid * 8 + k]; }
        partS[(size_t)blockIdx.x * 128 + tid] = s;
        partQ[(size_t)blockIdx.x * 128 + tid] = qq;
    }
}

// ---------------------------------------------------------------------------
// fold per-block partials -> per-channel scale/shift.  One block per channel.
// channel c lives in gemm-blocks bid = p*2 + (c>>7), entry (c&127); p<512.
// ---------------------------------------------------------------------------
__global__ __launch_bounds__(256) void bn_finalize(const float* __restrict__ pS,
                                                   const float* __restrict__ pQ,
                                                   const float* __restrict__ gamma,
                                                   const float* __restrict__ beta,
                                                   float* __restrict__ sc,
                                                   float* __restrict__ sh) {
    __shared__ float rs[256], rq[256];
    const int c = blockIdx.x;
    const int t = threadIdx.x;
    const int half = c >> 7, lo = c & 127;
    const size_t o1 = (size_t)(2 * t + half) * 128 + lo;
    const size_t o2 = (size_t)(2 * (t + 256) + half) * 128 + lo;
    rs[t] = pS[o1] + pS[o2];
    rq[t] = pQ[o1] + pQ[o2];
    __syncthreads();
    for (int k = 128; k > 0; k >>= 1) {
        if (t < k) { rs[t] += rs[t + k]; rq[t] += rq[t + k]; }
        __syncthreads();
    }
    if (t == 0) {
        const float inv = 1.f / (float)R_TOT;
        float mean = rs[0] * inv;
        float var  = rq[0] * inv - mean * mean;
        float a    = gamma[c] * rsqrtf(var + 1e-5f);
        sc[c] = a;
        sh[c] = beta[c] - mean * a;
    }
}

// ---------------------------------------------------------------------------
// apply BN+ReLU in place (bf16, layer-1 intermediate)
// ---------------------------------------------------------------------------
__global__ __launch_bounds__(256) void apply_bf16(__bf16* __restrict__ y,
                                                  const float* __restrict__ sc,
                                                  const float* __restrict__ sh) {
    __shared__ float scs[256], shs[256];
    scs[threadIdx.x] = sc[threadIdx.x];
    shs[threadIdx.x] = sh[threadIdx.x];
    __syncthreads();
    size_t i = ((size_t)blockIdx.x * 256 + threadIdx.x) * 8;
    int c0 = (int)(i & 255);
    bf16x8 v = *(const bf16x8*)(y + i);
#pragma unroll
    for (int e = 0; e < 8; ++e) {
        float f = fmaf((float)v[e], scs[c0 + e], shs[c0 + e]);
        v[e] = (__bf16)fmaxf(f, 0.f);
    }
    *(bf16x8*)(y + i) = v;
}

// ---------------------------------------------------------------------------
// apply BN+ReLU reading bf16 y2, writing fp32 output
// ---------------------------------------------------------------------------
__global__ __launch_bounds__(256) void apply_out(const __bf16* __restrict__ y,
                                                 const float* __restrict__ sc,
                                                 const float* __restrict__ sh,
                                                 float* __restrict__ out) {
    __shared__ float scs[256], shs[256];
    scs[threadIdx.x] = sc[threadIdx.x];
    shs[threadIdx.x] = sh[threadIdx.x];
    __syncthreads();
    size_t i = ((size_t)blockIdx.x * 256 + threadIdx.x) * 8;
    int c0 = (int)(i & 255);
    bf16x8 v = *(const bf16x8*)(y + i);
    f32x4 o0, o1;
#pragma unroll
    for (int e = 0; e < 4; ++e)
        o0[e] = fmaxf(fmaf((float)v[e], scs[c0 + e], shs[c0 + e]), 0.f);
#pragma unroll
    for (int e = 0; e < 4; ++e)
        o1[e] = fmaxf(fmaf((float)v[4 + e], scs[c0 + 4 + e], shs[c0 + 4 + e]), 0.f);
    *(f32x4*)(out + i)     = o0;
    *(f32x4*)(out + i + 4) = o1;
}

// ---------------------------------------------------------------------------
extern "C" void kernel_launch(void* const* d_in, const int* in_sizes, int n_in,
                              void* d_out, int out_size, void* d_ws, size_t ws_size,
                              hipStream_t stream) {
    const float* xyz1 = (const float*)d_in[0];
    const float* xyz2 = (const float*)d_in[1];
    const float* p1   = (const float*)d_in[2];
    const float* p2   = (const float*)d_in[3];
    const float* W1   = (const float*)d_in[4];
    // d_in[5] = b1  (cancels in batch-norm)
    const float* g1   = (const float*)d_in[6];
    const float* be1  = (const float*)d_in[7];
    const float* W2   = (const float*)d_in[8];
    // d_in[9] = b2  (cancels in batch-norm)
    const float* g2   = (const float*)d_in[10];
    const float* be2  = (const float*)d_in[11];
    float* out = (float*)d_out;

    // workspace layout (16B aligned), max ~76.9 MB:
    //   gidx4/sorted live in the old vals4/ci4 slot (dead after gemm_a_int /
    //   knn_sweep); y2b overlays them + zb/w4/p2b + p1b-head (all dead then)
    char* ws = (char*)d_ws;
    __bf16* y1b   = (__bf16*)(ws);                     // 33,554,432
    int4*   gidx4 = (int4*)  (ws + 33554432);          //  1,048,576
    float4* sorted= (float4*)(ws + 34603008);          //    262,144
    __bf16* zb    = (__bf16*)(ws + 41943040);          //  8,388,608
    float4* w4    = (float4*)(ws + 50331648);          //  1,048,576
    __bf16* p2b   = (__bf16*)(ws + 51380224);          //  8,388,608
    __bf16* p1b   = (__bf16*)(ws + 59768832);          // 16,777,216
    __bf16* y2b   = (__bf16*)(ws + 33554432);          // 33,554,432 (overlay)
    __bf16* wb1a  = (__bf16*)(ws + 76546048);          //     65,536
    __bf16* wb1b  = (__bf16*)(ws + 76611584);          //    131,072
    __bf16* wb2   = (__bf16*)(ws + 76742656);          //    131,072
    float*  sc1   = (float*) (ws + 76873728);
    float*  sh1   = sc1 + 256;
    float*  sc2   = sc1 + 512;
    float*  sh2   = sc1 + 768;

    float* partS1 = (float*)d_out;            // d_out dead until apply_out
    float* partQ1 = partS1 + 131072;
    float* partS2 = partS1 + 262144;
    float* partQ2 = partS1 + 393216;

    convert_sort<<<2112, 256, 0, stream>>>(xyz2, p1, p2, W1, W2,
                                           p1b, p2b, wb1a, wb1b, wb2, sorted);
    knn_sweep<<<512, 256, 0, stream>>>(xyz1, sorted, w4, gidx4);

    gemm_bt<C2, false><<<256, 256, 0, stream>>>(p2b, wb1b, zb, nullptr, nullptr);
    gemm_a_int<<<1024, 256, 0, stream>>>(p1b, wb1a, zb, gidx4, w4, y1b,
                                         partS1, partQ1);
    bn_finalize<<<256, 256, 0, stream>>>(partS1, partQ1, g1, be1, sc1, sh1);
    apply_bf16<<<8192, 256, 0, stream>>>(y1b, sc1, sh1);

    gemm_bt<H_OUT, true><<<1024, 256, 0, stream>>>(y1b, wb2, y2b, partS2, partQ2);
    bn_finalize<<<256, 256, 0, stream>>>(partS2, partQ2, g2, be2, sc2, sh2);
    apply_out<<<8192, 256, 0, stream>>>(y2b, sc2, sh2, out);
}

// Round 3
// 425.588 us; speedup vs baseline: 1.1994x; 1.1994x over previous
//
#include <hip/hip_runtime.h>
#include <hip/hip_bf16.h>
#include <stdint.h>

// Problem constants (fixed by setup_inputs)
#define B_SZ  8
#define N_Q   8192
#define M_PT  2048
#define C1    128
#define C2    256
#define CIN   384      // C1 + C2
#define H_OUT 256
#define R_TOT 65536    // B_SZ * N_Q

typedef __bf16 bf16x8 __attribute__((ext_vector_type(8)));
typedef __bf16 bf16x4 __attribute__((ext_vector_type(4)));
typedef float  f32x4  __attribute__((ext_vector_type(4)));

// Async global->LDS, 16B per lane. LDS dest is wave-uniform base + lane*16.
__device__ __forceinline__ void async_copy16(const void* g, void* l) {
    __builtin_amdgcn_global_load_lds(
        (const __attribute__((address_space(1))) unsigned int*)g,
        (__attribute__((address_space(3))) unsigned int*)l,
        16, 0, 0);
}

// ---------------------------------------------------------------------------
// K1: convert folds (p1/p2 -> bf16, W1 split, W2) + per-batch x-sort of xyz2
// (rank-by-count O(M^2)) + per-batch x-binning of queries (256-bin counting
// sort; any monotone binning gives x-sorted-by-bin order, which is all the
// sweep needs).  Sort/bin blocks FIRST (blockIdx 0..71) so they overlap the
// ~12 us of streaming converts.
// spts[b][rank] = (-2x, -2y, -2z, |p|^2)   (d' operands, bitwise-identical
//                                           to the round-2 passing kernel)
// sidx[b][rank] = original point index
// qord[b][pos]  = query indices in x-bin order
// ---------------------------------------------------------------------------
__global__ __launch_bounds__(256) void convert_sort(
    const float* __restrict__ xyz1, const float* __restrict__ xyz2,
    const float* __restrict__ p1,   const float* __restrict__ p2,
    const float* __restrict__ W1,   const float* __restrict__ W2,
    __bf16* __restrict__ p1b,  __bf16* __restrict__ p2b,
    __bf16* __restrict__ wb1a, __bf16* __restrict__ wb1b,
    __bf16* __restrict__ wb2,  float4* __restrict__ spts,
    int* __restrict__ sidx,    int* __restrict__ qord) {
    const int tid = threadIdx.x;

    if (blockIdx.x < 64) {   // ---- point-sort blocks: (b, chunk-of-256)
        __shared__ __attribute__((aligned(16))) float xs[M_PT];
        const int b  = blockIdx.x >> 3;
        const int ch = blockIdx.x & 7;
        const float* x2 = xyz2 + (size_t)b * M_PT * 3;
#pragma unroll
        for (int j = tid; j < M_PT; j += 256) xs[j] = x2[j * 3];
        __syncthreads();
        const int   i  = ch * 256 + tid;
        const float xi = xs[i];
        const float yi = x2[i * 3 + 1], zi = x2[i * 3 + 2];
        int rank = 0;
#pragma unroll 4
        for (int j = 0; j < M_PT; j += 4) {
            const float4 xv = *(const float4*)&xs[j];
            rank += (xv.x < xi || (xv.x == xi && (j + 0) < i)) ? 1 : 0;
            rank += (xv.y < xi || (xv.y == xi && (j + 1) < i)) ? 1 : 0;
            rank += (xv.z < xi || (xv.z == xi && (j + 2) < i)) ? 1 : 0;
            rank += (xv.w < xi || (xv.w == xi && (j + 3) < i)) ? 1 : 0;
        }
        const float pw = fmaf(xi, xi, fmaf(yi, yi, zi * zi));
        spts[(size_t)b * M_PT + rank] =
            make_float4(-2.f * xi, -2.f * yi, -2.f * zi, pw);
        sidx[(size_t)b * M_PT + rank] = i;
        return;
    }

    if (blockIdx.x < 72) {   // ---- query-binning blocks: one per batch
        __shared__ int hist[256], offs[256];
        const int b = blockIdx.x - 64;
        const float* x1 = xyz1 + (size_t)b * N_Q * 3;
        hist[tid] = 0;
        __syncthreads();
        int mybin[32];
#pragma unroll
        for (int k = 0; k < 32; ++k) {
            const int q = k * 256 + tid;
            const float x = x1[q * 3];
            int bin = (int)((x + 4.0f) * 32.0f);
            bin = min(max(bin, 0), 255);
            mybin[k] = bin;
            atomicAdd(&hist[bin], 1);
        }
        __syncthreads();
        offs[tid] = hist[tid];
        __syncthreads();
        for (int s = 1; s < 256; s <<= 1) {     // inclusive Hillis-Steele
            const int v = (tid >= s) ? offs[tid - s] : 0;
            __syncthreads();
            offs[tid] += v;
            __syncthreads();
        }
        hist[tid] = offs[tid] - hist[tid];      // exclusive base -> counter
        __syncthreads();
#pragma unroll
        for (int k = 0; k < 32; ++k) {
            const int pos = atomicAdd(&hist[mybin[k]], 1);
            qord[(size_t)b * N_Q + pos] = k * 256 + tid;
        }
        return;
    }

    // ---- convert blocks: cb in [0, 2048)
    const int cb  = blockIdx.x - 72;
    const int gid = cb * 256 + tid;           // 0..524287

    // p2 -> bf16 (4,194,304 elems = 524288 threads x 8)
    {
        const float4* src = (const float4*)p2 + (size_t)gid * 2;
        float4 a = src[0], bb = src[1];
        bf16x8 o;
        o[0]=(__bf16)a.x; o[1]=(__bf16)a.y; o[2]=(__bf16)a.z; o[3]=(__bf16)a.w;
        o[4]=(__bf16)bb.x; o[5]=(__bf16)bb.y; o[6]=(__bf16)bb.z; o[7]=(__bf16)bb.w;
        *(bf16x8*)(p2b + (size_t)gid * 8) = o;
    }
    // W1 split-convert (98304 elems) / W2 convert (65536 elems)
    if (cb < 384) {
        const int e = gid;                       // 0..98303
        const int o = e / 384, k = e - o * 384;
        __bf16 v = (__bf16)W1[e];
        if (k < C1) wb1a[o * C1 + k] = v;
        else        wb1b[o * C2 + (k - C1)] = v;
    } else if (cb < 640) {
        const int e = gid - 98304;               // 0..65535
        wb2[e] = (__bf16)W2[e];
    }
    // p1 -> bf16 (8,388,608 elems = 524288 threads x 16)
    {
        const float4* src = (const float4*)p1 + (size_t)gid * 4;
        float4 a = src[0], bb = src[1], cc = src[2], dd = src[3];
        bf16x8 o0, o1;
        o0[0]=(__bf16)a.x; o0[1]=(__bf16)a.y; o0[2]=(__bf16)a.z; o0[3]=(__bf16)a.w;
        o0[4]=(__bf16)bb.x; o0[5]=(__bf16)bb.y; o0[6]=(__bf16)bb.z; o0[7]=(__bf16)bb.w;
        o1[0]=(__bf16)cc.x; o1[1]=(__bf16)cc.y; o1[2]=(__bf16)cc.z; o1[3]=(__bf16)cc.w;
        o1[4]=(__bf16)dd.x; o1[5]=(__bf16)dd.y; o1[6]=(__bf16)dd.z; o1[7]=(__bf16)dd.w;
        *(bf16x8*)(p1b + (size_t)gid * 16)     = o0;
        *(bf16x8*)(p1b + (size_t)gid * 16 + 8) = o1;
    }
}

// ---------------------------------------------------------------------------
// K2: broadcast-window sweep KNN.
// Wave = 32 x-adjacent (binned) queries; lane l and l+32 hold the SAME query
// (side 0 = left sweep, side 1 = right sweep).  The wave expands one shared
// window outward from the common lower-bound: per step each half-wave reads
// one wave-uniform LDS point (broadcast, conflict-free) and inserts it into
// its per-lane top-3 (value + rank; index looked up at the end).  Each side's
// stop condition latches independently: remaining points on a side have true
// dist >= (frontier dx)^2, so stop when that bound >= merged-v2 + |q|^2 +
// 1e-3 guard (v2 is monotone non-increasing, so latching is sound).
// d' operands come precomputed from spts => bitwise-identical selection to
// the round-2 passing kernel.  Block = 4 waves = 128 queries; grid = 512.
// ---------------------------------------------------------------------------
__global__ __launch_bounds__(256) void knn_sweep(
    const float* __restrict__ xyz1, const float4* __restrict__ spts,
    const int* __restrict__ sidx,   const int* __restrict__ qord,
    float4* __restrict__ w4, int4* __restrict__ gidx4) {
    __shared__ __attribute__((aligned(16))) float4 pts[M_PT];   // 32 KB
    __shared__ __attribute__((aligned(16))) int   idxs[M_PT];   //  8 KB
    const int tid  = threadIdx.x;
    const int b    = blockIdx.x >> 6;        // 64 blocks per batch
    const int qb   = blockIdx.x & 63;        // 128 queries per block
    const int wave = tid >> 6, lane = tid & 63;

    {   // stage spts[b] (2048 float4) + sidx[b] (2048 int), async 16B/lane
        const float4* src = spts + (size_t)b * M_PT;
#pragma unroll
        for (int j = 0; j < 8; ++j)
            async_copy16(src + j * 256 + wave * 64 + lane,
                         (char*)pts + ((j * 256 + wave * 64) << 4));
        const float4* si = (const float4*)(sidx + (size_t)b * M_PT);
#pragma unroll
        for (int j = 0; j < 2; ++j)
            async_copy16(si + j * 256 + wave * 64 + lane,
                         (char*)idxs + ((j * 256 + wave * 64) << 4));
    }
    __syncthreads();

    const int side = lane >> 5;                    // 0 = left, 1 = right
    const int sp   = qb * 128 + wave * 32 + (lane & 31);
    const int qloc = qord[(size_t)b * N_Q + sp];
    const int qid  = b * N_Q + qloc;
    const float* qp = xyz1 + (size_t)qid * 3;
    const float qx = qp[0], qy = qp[1], qz = qp[2];
    const float n1q = fmaf(qx, qx, fmaf(qy, qy, qz * qz));
    const float sq  = -2.f * qx;

    // lower_bound: first rank with x >= qx  (pts[].x stores -2x, descending)
    int lo = 0, hi = M_PT;
#pragma unroll
    for (int s = 0; s < 11; ++s) {
        const int mid = (lo + hi) >> 1;
        const bool gt = pts[mid].x > sq;           // -2x > -2qx <=> x < qx
        lo = gt ? mid + 1 : lo;
        hi = gt ? hi : mid;
    }

    int lomin = lo;                                // shared window origin
#pragma unroll
    for (int s = 1; s < 64; s <<= 1)
        lomin = min(lomin, __shfl_xor(lomin, s));

    float v0 = 3.4e38f, v1 = 3.4e38f, v2 = 3.4e38f;
    int   r0 = 0, r1 = 0, r2 = 0;
    int pl = lomin - 1, pr = lomin;
    bool dl = false, dr = false;

    for (int it = 0; it < 272 && !(dl && dr); ++it) {
#pragma unroll
        for (int k = 0; k < 8; ++k) {
            const int  jm  = side ? (pr + k) : (pl - k);
            const bool val = side ? (!dr && jm < M_PT) : (!dl && jm >= 0);
            const int  rk  = jm & (M_PT - 1);
            const float4 p = pts[rk];              // wave-uniform per half
            float d = fmaf(p.x, qx, fmaf(p.y, qy, fmaf(p.z, qz, p.w)));
            d = val ? d : 3.4e38f;
            const bool c0 = d < v0, c1 = d < v1, c2 = d < v2;
            const float n1v = __builtin_amdgcn_fmed3f(d, v0, v1);
            const float n2v = __builtin_amdgcn_fmed3f(d, v1, v2);
            r2 = c1 ? r1 : (c2 ? rk : r2);
            r1 = c0 ? r0 : (c1 ? rk : r1);
            r0 = c0 ? rk : r0;
            v0 = fminf(d, v0); v1 = n1v; v2 = n2v;
        }
        if (!dl) pl -= 8;
        if (!dr) pr += 8;
        const float v2m = fminf(v2, __shfl_xor(v2, 32));
        const float thr = fminf(v2m + n1q + 1e-3f, 3.0e38f);
        const float sxl = pts[pl & (M_PT - 1)].x;  // uniform broadcast reads
        const float sxr = pts[pr & (M_PT - 1)].x;
        const float tl = fmaxf(fmaf(0.5f, sxl, qx), 0.f);    // qx - x[pl]
        const float tr = fmaxf(-fmaf(0.5f, sxr, qx), 0.f);   // x[pr] - qx
        const float bl = (pl >= 0)   ? tl * tl : 3.4e38f;
        const float br = (pr < M_PT) ? tr * tr : 3.4e38f;
        dl = dl || __all(bl >= thr);
        dr = dr || __all(br >= thr);
    }

    // merge partner's triple (sides processed disjoint point sets)
    const float m0 = __shfl_xor(v0, 32), m1 = __shfl_xor(v1, 32),
                m2 = __shfl_xor(v2, 32);
    const int   s0 = __shfl_xor(r0, 32), s1 = __shfl_xor(r1, 32),
                s2 = __shfl_xor(r2, 32);
#pragma unroll
    for (int t = 0; t < 3; ++t) {
        const float d = (t == 0) ? m0 : (t == 1) ? m1 : m2;
        const int  rk = (t == 0) ? s0 : (t == 1) ? s1 : s2;
        const bool c0 = d < v0, c1 = d < v1, c2 = d < v2;
        const float n1v = __builtin_amdgcn_fmed3f(d, v0, v1);
        const float n2v = __builtin_amdgcn_fmed3f(d, v1, v2);
        r2 = c1 ? r1 : (c2 ? rk : r2);
        r1 = c0 ? r0 : (c1 ? rk : r1);
        r0 = c0 ? rk : r0;
        v0 = fminf(d, v0); v1 = n1v; v2 = n2v;
    }

    if (side == 0) {   // weights: identical formula to the passing rounds
        const int i0 = idxs[r0], i1 = idxs[r1], i2 = idxs[r2];
        const float rr0 = 1.f / ((v0 + n1q) + 1e-8f);
        const float rr1 = 1.f / ((v1 + n1q) + 1e-8f);
        const float rr2 = 1.f / ((v2 + n1q) + 1e-8f);
        const float rs  = 1.f / (rr0 + rr1 + rr2);
        w4[qid]    = make_float4(rr0 * rs, rr1 * rs, rr2 * rs, 0.f);
        gidx4[qid] = make_int4(i0, i1, i2, 0);
    }
}

// ---------------------------------------------------------------------------
// bf16 MFMA GEMM (m97 structure), optional fused BN-stats partials.
// C stride is H_OUT=256 for all uses (Z, y2).  grid = (rows/128)*2.
// ---------------------------------------------------------------------------
template <int K, bool STATS>
__global__ __launch_bounds__(256, 2) void gemm_bt(const __bf16* __restrict__ A,
                                                  const __bf16* __restrict__ Bw,
                                                  __bf16* __restrict__ Cout,
                                                  float* __restrict__ partS,
                                                  float* __restrict__ partQ) {
    __shared__ __attribute__((aligned(16))) __bf16 As[128 * 32];
    __shared__ __attribute__((aligned(16))) __bf16 Bs[128 * 32];
    const int tid  = threadIdx.x;
    const int wave = tid >> 6, lane = tid & 63;
    const int wm = wave >> 1, wn = wave & 1;
    const int quad = lane >> 4, r16 = lane & 15;
    const int bx = blockIdx.x & 1, by = blockIdx.x >> 1;
    const int l4 = lane >> 2, lk = (lane & 3) * 8;

    f32x4 acc[4][4] = {};

    const __bf16* gA = A  + (size_t)(by * 128 + wave * 32 + l4) * K + lk;
    const __bf16* gB = Bw + (size_t)(bx * 128 + wave * 32 + l4) * K + lk;
    char* lA = (char*)As + wave * 2048;
    char* lB = (char*)Bs + wave * 2048;

    for (int k0 = 0; k0 < K; k0 += 32) {
        async_copy16(gA + k0,                  lA);
        async_copy16(gA + k0 + (size_t)16 * K, lA + 1024);
        async_copy16(gB + k0,                  lB);
        async_copy16(gB + k0 + (size_t)16 * K, lB + 1024);
        __syncthreads();

        bf16x8 af[4], bf[4];
#pragma unroll
        for (int t = 0; t < 4; ++t)
            af[t] = *(const bf16x8*)(As + (wm * 64 + t * 16 + r16) * 32 + quad * 8);
#pragma unroll
        for (int u = 0; u < 4; ++u)
            bf[u] = *(const bf16x8*)(Bs + (wn * 64 + u * 16 + r16) * 32 + quad * 8);
#pragma unroll
        for (int t = 0; t < 4; ++t)
#pragma unroll
            for (int u = 0; u < 4; ++u)
                acc[t][u] = __builtin_amdgcn_mfma_f32_16x16x32_bf16(af[t], bf[u], acc[t][u], 0, 0, 0);
        __syncthreads();
    }

    // C/D layout col=lane&15, row=(lane>>4)*4+reg [m89-verified]
#pragma unroll
    for (int t = 0; t < 4; ++t) {
#pragma unroll
        for (int u = 0; u < 4; ++u) {
            const int col = bx * 128 + wn * 64 + u * 16 + r16;
#pragma unroll
            for (int r = 0; r < 4; ++r) {
                const int row = by * 128 + wm * 64 + t * 16 + quad * 4 + r;
                Cout[(size_t)row * H_OUT + col] = (__bf16)acc[t][u][r];
            }
        }
    }

    if constexpr (STATS) {
        float* redS = (float*)As;          // [col(128)][slot(8)]
        float* redQ = ((float*)As) + 1024;
        const int slot = wm * 4 + quad;
#pragma unroll
        for (int u = 0; u < 4; ++u) {
            float s = 0.f, qq = 0.f;
#pragma unroll
            for (int t = 0; t < 4; ++t)
#pragma unroll
                for (int r = 0; r < 4; ++r) { float v = acc[t][u][r]; s += v; qq = fmaf(v, v, qq); }
            const int col = wn * 64 + u * 16 + r16;
            redS[col * 8 + slot] = s;
            redQ[col * 8 + slot] = qq;
        }
        __syncthreads();
        if (tid < 128) {
            float s = 0.f, qq = 0.f;
#pragma unroll
            for (int k = 0; k < 8; ++k) { s += redS[tid * 8 + k]; qq += redQ[tid * 8 + k]; }
            partS[(size_t)blockIdx.x * 128 + tid] = s;
            partQ[(size_t)blockIdx.x * 128 + tid] = qq;
        }
    }
}

// ---------------------------------------------------------------------------
// GEMM-A (K=128) + fused interpolation epilogue + BN-stats:
//   y1 = p1b @ wb1a^T + sum_k w_k * Z[idx_k]      (linearity of interp)
// Z rows are L2-resident (8.4 MB); gathers are 16-lane-contiguous 2B loads.
// grid = 512*2 = 1024 blocks of 256.  (idx/w come directly from knn_sweep.)
// ---------------------------------------------------------------------------
__global__ __launch_bounds__(256, 2) void gemm_a_int(
    const __bf16* __restrict__ A,  const __bf16* __restrict__ Bw,
    const __bf16* __restrict__ zb, const int4* __restrict__ gidx4,
    const float4* __restrict__ w4, __bf16* __restrict__ Cout,
    float* __restrict__ partS, float* __restrict__ partQ) {
    constexpr int K = C1;   // 128
    __shared__ __attribute__((aligned(16))) __bf16 As[128 * 32];
    __shared__ __attribute__((aligned(16))) __bf16 Bs[128 * 32];
    const int tid  = threadIdx.x;
    const int wave = tid >> 6, lane = tid & 63;
    const int wm = wave >> 1, wn = wave & 1;
    const int quad = lane >> 4, r16 = lane & 15;
    const int bx = blockIdx.x & 1, by = blockIdx.x >> 1;
    const int l4 = lane >> 2, lk = (lane & 3) * 8;

    f32x4 acc[4][4] = {};

    const __bf16* gA = A  + (size_t)(by * 128 + wave * 32 + l4) * K + lk;
    const __bf16* gB = Bw + (size_t)(bx * 128 + wave * 32 + l4) * K + lk;
    char* lA = (char*)As + wave * 2048;
    char* lB = (char*)Bs + wave * 2048;

    for (int k0 = 0; k0 < K; k0 += 32) {
        async_copy16(gA + k0,                  lA);
        async_copy16(gA + k0 + (size_t)16 * K, lA + 1024);
        async_copy16(gB + k0,                  lB);
        async_copy16(gB + k0 + (size_t)16 * K, lB + 1024);
        __syncthreads();

        bf16x8 af[4], bf[4];
#pragma unroll
        for (int t = 0; t < 4; ++t)
            af[t] = *(const bf16x8*)(As + (wm * 64 + t * 16 + r16) * 32 + quad * 8);
#pragma unroll
        for (int u = 0; u < 4; ++u)
            bf[u] = *(const bf16x8*)(Bs + (wn * 64 + u * 16 + r16) * 32 + quad * 8);
#pragma unroll
        for (int t = 0; t < 4; ++t)
#pragma unroll
            for (int u = 0; u < 4; ++u)
                acc[t][u] = __builtin_amdgcn_mfma_f32_16x16x32_bf16(af[t], bf[u], acc[t][u], 0, 0, 0);
        __syncthreads();
    }

    // stage per-row (idx0..2, w0..2) into As (4 KB of the free 8 KB)
    if (tid < 128) {
        const int q = by * 128 + tid;
        ((int4*)As)[tid * 2]       = gidx4[q];
        ((float4*)As)[tid * 2 + 1] = w4[q];
    }
    __syncthreads();

    // add interpolated Z rows into the accumulators
    const int bbase = (by >> 6) * M_PT;   // 64 row-blocks per batch
#pragma unroll
    for (int t = 0; t < 4; ++t) {
#pragma unroll
        for (int r = 0; r < 4; ++r) {
            const int rl = wm * 64 + t * 16 + quad * 4 + r;   // row-in-block
            const int4   ii = ((const int4*)As)[rl * 2];      // broadcast read
            const float4 ww = ((const float4*)As)[rl * 2 + 1];
            const __bf16* z0 = zb + (size_t)(bbase + ii.x) * H_OUT;
            const __bf16* z1 = zb + (size_t)(bbase + ii.y) * H_OUT;
            const __bf16* z2 = zb + (size_t)(bbase + ii.z) * H_OUT;
#pragma unroll
            for (int u = 0; u < 4; ++u) {
                const int col = bx * 128 + wn * 64 + u * 16 + r16;
                acc[t][u][r] += ww.x * (float)z0[col] + ww.y * (float)z1[col]
                              + ww.z * (float)z2[col];
            }
        }
    }

    // C store (bf16 y1)
#pragma unroll
    for (int t = 0; t < 4; ++t) {
#pragma unroll
        for (int u = 0; u < 4; ++u) {
            const int col = bx * 128 + wn * 64 + u * 16 + r16;
#pragma unroll
            for (int r = 0; r < 4; ++r) {
                const int row = by * 128 + wm * 64 + t * 16 + quad * 4 + r;
                Cout[(size_t)row * H_OUT + col] = (__bf16)acc[t][u][r];
            }
        }
    }

    __syncthreads();   // idx/w reads done before stats overwrite As
    float* redS = (float*)As;
    float* redQ = ((float*)As) + 1024;
    const int slot = wm * 4 + quad;
#pragma unroll
    for (int u = 0; u < 4; ++u) {
        float s = 0.f, qq = 0.f;
#pragma unroll
        for (int t = 0; t < 4; ++t)
#pragma unroll
            for (int r = 0; r < 4; ++r) { float v = acc[t][u][r]; s += v; qq = fmaf(v, v, qq); }
        const int col = wn * 64 + u * 16 + r16;
        redS[col * 8 + slot] = s;
        redQ[col * 8 + slot] = qq;
    }
    __syncthreads();
    if (tid < 128) {
        float s = 0.f, qq = 0.f;
#pragma unroll
        for (int k = 0; k < 8; ++k) { s += redS[tid * 8 + k]; qq += redQ[tid * 8 + k]; }
        partS[(size_t)blockIdx.x * 128 + tid] = s;
        partQ[(size_t)blockIdx.x * 128 + tid] = qq;
    }
}

// ---------------------------------------------------------------------------
// fold per-block partials -> per-channel scale/shift.  One block per channel.
// channel c lives in gemm-blocks bid = p*2 + (c>>7), entry (c&127); p<512.
// ---------------------------------------------------------------------------
__global__ __launch_bounds__(256) void bn_finalize(const float* __restrict__ pS,
                                                   const float* __restrict__ pQ,
                                                   const float* __restrict__ gamma,
                                                   const float* __restrict__ beta,
                                                   float* __restrict__ sc,
                                                   float* __restrict__ sh) {
    __shared__ float rs[256], rq[256];
    const int c = blockIdx.x;
    const int t = threadIdx.x;
    const int half = c >> 7, lo = c & 127;
    const size_t o1 = (size_t)(2 * t + half) * 128 + lo;
    const size_t o2 = (size_t)(2 * (t + 256) + half) * 128 + lo;
    rs[t] = pS[o1] + pS[o2];
    rq[t] = pQ[o1] + pQ[o2];
    __syncthreads();
    for (int k = 128; k > 0; k >>= 1) {
        if (t < k) { rs[t] += rs[t + k]; rq[t] += rq[t + k]; }
        __syncthreads();
    }
    if (t == 0) {
        const float inv = 1.f / (float)R_TOT;
        float mean = rs[0] * inv;
        float var  = rq[0] * inv - mean * mean;
        float a    = gamma[c] * rsqrtf(var + 1e-5f);
        sc[c] = a;
        sh[c] = beta[c] - mean * a;
    }
}

// ---------------------------------------------------------------------------
// apply BN+ReLU in place (bf16, layer-1 intermediate)
// ---------------------------------------------------------------------------
__global__ __launch_bounds__(256) void apply_bf16(__bf16* __restrict__ y,
                                                  const float* __restrict__ sc,
                                                  const float* __restrict__ sh) {
    __shared__ float scs[256], shs[256];
    scs[threadIdx.x] = sc[threadIdx.x];
    shs[threadIdx.x] = sh[threadIdx.x];
    __syncthreads();
    size_t i = ((size_t)blockIdx.x * 256 + threadIdx.x) * 8;
    int c0 = (int)(i & 255);
    bf16x8 v = *(const bf16x8*)(y + i);
#pragma unroll
    for (int e = 0; e < 8; ++e) {
        float f = fmaf((float)v[e], scs[c0 + e], shs[c0 + e]);
        v[e] = (__bf16)fmaxf(f, 0.f);
    }
    *(bf16x8*)(y + i) = v;
}

// ---------------------------------------------------------------------------
// apply BN+ReLU reading bf16 y2, writing fp32 output
// ---------------------------------------------------------------------------
__global__ __launch_bounds__(256) void apply_out(const __bf16* __restrict__ y,
                                                 const float* __restrict__ sc,
                                                 const float* __restrict__ sh,
                                                 float* __restrict__ out) {
    __shared__ float scs[256], shs[256];
    scs[threadIdx.x] = sc[threadIdx.x];
    shs[threadIdx.x] = sh[threadIdx.x];
    __syncthreads();
    size_t i = ((size_t)blockIdx.x * 256 + threadIdx.x) * 8;
    int c0 = (int)(i & 255);
    bf16x8 v = *(const bf16x8*)(y + i);
    f32x4 o0, o1;
#pragma unroll
    for (int e = 0; e < 4; ++e)
        o0[e] = fmaxf(fmaf((float)v[e], scs[c0 + e], shs[c0 + e]), 0.f);
#pragma unroll
    for (int e = 0; e < 4; ++e)
        o1[e] = fmaxf(fmaf((float)v[4 + e], scs[c0 + 4 + e], shs[c0 + 4 + e]), 0.f);
    *(f32x4*)(out + i)     = o0;
    *(f32x4*)(out + i + 4) = o1;
}

// ---------------------------------------------------------------------------
extern "C" void kernel_launch(void* const* d_in, const int* in_sizes, int n_in,
                              void* d_out, int out_size, void* d_ws, size_t ws_size,
                              hipStream_t stream) {
    const float* xyz1 = (const float*)d_in[0];
    const float* xyz2 = (const float*)d_in[1];
    const float* p1   = (const float*)d_in[2];
    const float* p2   = (const float*)d_in[3];
    const float* W1   = (const float*)d_in[4];
    // d_in[5] = b1  (cancels in batch-norm)
    const float* g1   = (const float*)d_in[6];
    const float* be1  = (const float*)d_in[7];
    const float* W2   = (const float*)d_in[8];
    // d_in[9] = b2  (cancels in batch-norm)
    const float* g2   = (const float*)d_in[10];
    const float* be2  = (const float*)d_in[11];
    float* out = (float*)d_out;

    // workspace layout (16B aligned), max ~76.9 MB:
    //   gidx4/spts/sidx/qord live in the y2b overlay region (all dead after
    //   gemm_a_int / knn_sweep, before gemm_bt<H_OUT> writes y2b)
    char* ws = (char*)d_ws;
    __bf16* y1b   = (__bf16*)(ws);                     // 33,554,432
    int4*   gidx4 = (int4*)  (ws + 33554432);          //  1,048,576
    float4* spts  = (float4*)(ws + 34603008);          //    262,144
    int*    sidx  = (int*)   (ws + 34865152);          //     65,536
    int*    qord  = (int*)   (ws + 34930688);          //    262,144
    __bf16* zb    = (__bf16*)(ws + 41943040);          //  8,388,608
    float4* w4    = (float4*)(ws + 50331648);          //  1,048,576
    __bf16* p2b   = (__bf16*)(ws + 51380224);          //  8,388,608
    __bf16* p1b   = (__bf16*)(ws + 59768832);          // 16,777,216
    __bf16* y2b   = (__bf16*)(ws + 33554432);          // 33,554,432 (overlay)
    __bf16* wb1a  = (__bf16*)(ws + 76546048);          //     65,536
    __bf16* wb1b  = (__bf16*)(ws + 76611584);          //    131,072
    __bf16* wb2   = (__bf16*)(ws + 76742656);          //    131,072
    float*  sc1   = (float*) (ws + 76873728);
    float*  sh1   = sc1 + 256;
    float*  sc2   = sc1 + 512;
    float*  sh2   = sc1 + 768;

    float* partS1 = (float*)d_out;            // d_out dead until apply_out
    float* partQ1 = partS1 + 131072;
    float* partS2 = partS1 + 262144;
    float* partQ2 = partS1 + 393216;

    convert_sort<<<2120, 256, 0, stream>>>(xyz1, xyz2, p1, p2, W1, W2,
                                           p1b, p2b, wb1a, wb1b, wb2,
                                           spts, sidx, qord);
    knn_sweep<<<512, 256, 0, stream>>>(xyz1, spts, sidx, qord, w4, gidx4);

    gemm_bt<C2, false><<<256, 256, 0, stream>>>(p2b, wb1b, zb, nullptr, nullptr);
    gemm_a_int<<<1024, 256, 0, stream>>>(p1b, wb1a, zb, gidx4, w4, y1b,
                                         partS1, partQ1);
    bn_finalize<<<256, 256, 0, stream>>>(partS1, partQ1, g1, be1, sc1, sh1);
    apply_bf16<<<8192, 256, 0, stream>>>(y1b, sc1, sh1);

    gemm_bt<H_OUT, true><<<1024, 256, 0, stream>>>(y1b, wb2, y2b, partS2, partQ2);
    bn_finalize<<<256, 256, 0, stream>>>(partS2, partQ2, g2, be2, sc2, sh2);
    apply_out<<<8192, 256, 0, stream>>>(y2b, sc2, sh2, out);
}

// Round 4
// 380.927 us; speedup vs baseline: 1.3401x; 1.1172x over previous
//
#include <hip/hip_runtime.h>
#include <hip/hip_bf16.h>
#include <stdint.h>

// Problem constants (fixed by setup_inputs)
#define B_SZ  8
#define N_Q   8192
#define M_PT  2048
#define C1    128
#define C2    256
#define CIN   384      // C1 + C2
#define H_OUT 256
#define R_TOT 65536    // B_SZ * N_Q

typedef __bf16 bf16x8 __attribute__((ext_vector_type(8)));
typedef __bf16 bf16x4 __attribute__((ext_vector_type(4)));
typedef float  f32x4  __attribute__((ext_vector_type(4)));

// Async global->LDS, 16B per lane. LDS dest is wave-uniform base + lane*16.
__device__ __forceinline__ void async_copy16(const void* g, void* l) {
    __builtin_amdgcn_global_load_lds(
        (const __attribute__((address_space(1))) unsigned int*)g,
        (__attribute__((address_space(3))) unsigned int*)l,
        16, 0, 0);
}

// ---------------------------------------------------------------------------
// K1: convert folds (p1/p2 -> bf16, W1 split, W2) + per-batch x-sort of xyz2
// (rank-by-count O(M^2)) + per-batch x-binning of queries (256-bin counting
// sort).  Sort/bin blocks FIRST (blockIdx 0..71) so they overlap the ~12 us
// of streaming converts.
// spts[b][rank] = (-2x, -2y, -2z, |p|^2)   (d' operands, bitwise-identical
//                                           to the round-2/3 passing kernels)
// sidx[b][rank] = original point index
// qord[b][pos]  = query indices in x-bin order
// ---------------------------------------------------------------------------
__global__ __launch_bounds__(256) void convert_sort(
    const float* __restrict__ xyz1, const float* __restrict__ xyz2,
    const float* __restrict__ p1,   const float* __restrict__ p2,
    const float* __restrict__ W1,   const float* __restrict__ W2,
    __bf16* __restrict__ p1b,  __bf16* __restrict__ p2b,
    __bf16* __restrict__ wb1a, __bf16* __restrict__ wb1b,
    __bf16* __restrict__ wb2,  float4* __restrict__ spts,
    int* __restrict__ sidx,    int* __restrict__ qord) {
    const int tid = threadIdx.x;

    if (blockIdx.x < 64) {   // ---- point-sort blocks: (b, chunk-of-256)
        __shared__ __attribute__((aligned(16))) float xs[M_PT];
        const int b  = blockIdx.x >> 3;
        const int ch = blockIdx.x & 7;
        const float* x2 = xyz2 + (size_t)b * M_PT * 3;
#pragma unroll
        for (int j = tid; j < M_PT; j += 256) xs[j] = x2[j * 3];
        __syncthreads();
        const int   i  = ch * 256 + tid;
        const float xi = xs[i];
        const float yi = x2[i * 3 + 1], zi = x2[i * 3 + 2];
        int rank = 0;
#pragma unroll 4
        for (int j = 0; j < M_PT; j += 4) {
            const float4 xv = *(const float4*)&xs[j];
            rank += (xv.x < xi || (xv.x == xi && (j + 0) < i)) ? 1 : 0;
            rank += (xv.y < xi || (xv.y == xi && (j + 1) < i)) ? 1 : 0;
            rank += (xv.z < xi || (xv.z == xi && (j + 2) < i)) ? 1 : 0;
            rank += (xv.w < xi || (xv.w == xi && (j + 3) < i)) ? 1 : 0;
        }
        const float pw = fmaf(xi, xi, fmaf(yi, yi, zi * zi));
        spts[(size_t)b * M_PT + rank] =
            make_float4(-2.f * xi, -2.f * yi, -2.f * zi, pw);
        sidx[(size_t)b * M_PT + rank] = i;
        return;
    }

    if (blockIdx.x < 72) {   // ---- query-binning blocks: one per batch
        __shared__ int hist[256], offs[256];
        const int b = blockIdx.x - 64;
        const float* x1 = xyz1 + (size_t)b * N_Q * 3;
        hist[tid] = 0;
        __syncthreads();
        int mybin[32];
#pragma unroll
        for (int k = 0; k < 32; ++k) {
            const int q = k * 256 + tid;
            const float x = x1[q * 3];
            int bin = (int)((x + 4.0f) * 32.0f);
            bin = min(max(bin, 0), 255);
            mybin[k] = bin;
            atomicAdd(&hist[bin], 1);
        }
        __syncthreads();
        offs[tid] = hist[tid];
        __syncthreads();
        for (int s = 1; s < 256; s <<= 1) {     // inclusive Hillis-Steele
            const int v = (tid >= s) ? offs[tid - s] : 0;
            __syncthreads();
            offs[tid] += v;
            __syncthreads();
        }
        hist[tid] = offs[tid] - hist[tid];      // exclusive base -> counter
        __syncthreads();
#pragma unroll
        for (int k = 0; k < 32; ++k) {
            const int pos = atomicAdd(&hist[mybin[k]], 1);
            qord[(size_t)b * N_Q + pos] = k * 256 + tid;
        }
        return;
    }

    // ---- convert blocks: cb in [0, 2048)
    const int cb  = blockIdx.x - 72;
    const int gid = cb * 256 + tid;           // 0..524287

    // p2 -> bf16 (4,194,304 elems = 524288 threads x 8)
    {
        const float4* src = (const float4*)p2 + (size_t)gid * 2;
        float4 a = src[0], bb = src[1];
        bf16x8 o;
        o[0]=(__bf16)a.x; o[1]=(__bf16)a.y; o[2]=(__bf16)a.z; o[3]=(__bf16)a.w;
        o[4]=(__bf16)bb.x; o[5]=(__bf16)bb.y; o[6]=(__bf16)bb.z; o[7]=(__bf16)bb.w;
        *(bf16x8*)(p2b + (size_t)gid * 8) = o;
    }
    // W1 split-convert (98304 elems) / W2 convert (65536 elems)
    if (cb < 384) {
        const int e = gid;                       // 0..98303
        const int o = e / 384, k = e - o * 384;
        __bf16 v = (__bf16)W1[e];
        if (k < C1) wb1a[o * C1 + k] = v;
        else        wb1b[o * C2 + (k - C1)] = v;
    } else if (cb < 640) {
        const int e = gid - 98304;               // 0..65535
        wb2[e] = (__bf16)W2[e];
    }
    // p1 -> bf16 (8,388,608 elems = 524288 threads x 16)
    {
        const float4* src = (const float4*)p1 + (size_t)gid * 4;
        float4 a = src[0], bb = src[1], cc = src[2], dd = src[3];
        bf16x8 o0, o1;
        o0[0]=(__bf16)a.x; o0[1]=(__bf16)a.y; o0[2]=(__bf16)a.z; o0[3]=(__bf16)a.w;
        o0[4]=(__bf16)bb.x; o0[5]=(__bf16)bb.y; o0[6]=(__bf16)bb.z; o0[7]=(__bf16)bb.w;
        o1[0]=(__bf16)cc.x; o1[1]=(__bf16)cc.y; o1[2]=(__bf16)cc.z; o1[3]=(__bf16)cc.w;
        o1[4]=(__bf16)dd.x; o1[5]=(__bf16)dd.y; o1[6]=(__bf16)dd.z; o1[7]=(__bf16)dd.w;
        *(bf16x8*)(p1b + (size_t)gid * 16)     = o0;
        *(bf16x8*)(p1b + (size_t)gid * 16 + 8) = o1;
    }
}

// ---------------------------------------------------------------------------
// K2: decoupled per-lane sweep KNN.
// Pair = (even lane, odd lane) = one query: even sweeps LEFT, odd sweeps
// RIGHT from the query's lower-bound rank.  Wave = 32 consecutive x-sorted
// queries, so per-lane LDS addresses are nearly identical across the wave
// (<=2-way bank aliasing = free).  Each lane has its OWN pointer and its OWN
// termination (remaining points on its side satisfy true-dist >= frontier
// dx^2; stop when that >= min(v2, partner v2) + |q|^2 + 1e-3 guard).
// Finished lanes are exec-masked off (if (!done)) => zero wasted VALU; the
// partner-v2 shfl sits OUTSIDE the masked region so both lanes are active
// at the exchange (bpermute from an inactive lane returns 0 => unsafe).
// Stale partner v2 is sound: v2 only decreases, so stopping early on a
// larger threshold is conservative... (it isn't early: threshold only
// shrinks later, and bnd >= thr stays true as thr decreases).
// d' operands from spts => selection bitwise-identical to passing rounds.
// Block = 4 waves = 128 queries; grid = 512 (2 blocks/CU, 8 waves/CU).
// ---------------------------------------------------------------------------
__global__ __launch_bounds__(256) void knn_sweep(
    const float* __restrict__ xyz1, const float4* __restrict__ spts,
    const int* __restrict__ sidx,   const int* __restrict__ qord,
    float4* __restrict__ w4, int4* __restrict__ gidx4) {
    __shared__ __attribute__((aligned(16))) float4 pts[M_PT];   // 32 KB
    __shared__ __attribute__((aligned(16))) int   idxs[M_PT];   //  8 KB
    const int tid  = threadIdx.x;
    const int b    = blockIdx.x >> 6;        // 64 blocks per batch
    const int qb   = blockIdx.x & 63;        // 128 queries per block
    const int wave = tid >> 6, lane = tid & 63;

    {   // stage spts[b] (2048 float4) + sidx[b] (2048 int), async 16B/lane
        const float4* src = spts + (size_t)b * M_PT;
#pragma unroll
        for (int j = 0; j < 8; ++j)
            async_copy16(src + j * 256 + wave * 64 + lane,
                         (char*)pts + ((j * 256 + wave * 64) << 4));
        const float4* si = (const float4*)(sidx + (size_t)b * M_PT);
#pragma unroll
        for (int j = 0; j < 2; ++j)
            async_copy16(si + j * 256 + wave * 64 + lane,
                         (char*)idxs + ((j * 256 + wave * 64) << 4));
    }
    __syncthreads();

    const int side = lane & 1;                     // 0 = left, 1 = right
    const int sp   = qb * 128 + wave * 32 + (lane >> 1);
    const int qloc = qord[(size_t)b * N_Q + sp];
    const int qid  = b * N_Q + qloc;
    const float* qp = xyz1 + (size_t)qid * 3;
    const float qx = qp[0], qy = qp[1], qz = qp[2];
    const float n1q = fmaf(qx, qx, fmaf(qy, qy, qz * qz));
    const float sq  = -2.f * qx;

    // lower_bound: first rank with x >= qx  (pts[].x stores -2x, descending)
    int lo = 0, hi = M_PT;
#pragma unroll
    for (int s = 0; s < 11; ++s) {
        const int mid = (lo + hi) >> 1;
        const bool gt = pts[mid].x > sq;           // -2x > -2qx <=> x < qx
        lo = gt ? mid + 1 : lo;
        hi = gt ? hi : mid;
    }

    float v0 = 3.4e38f, v1 = 3.4e38f, v2 = 3.4e38f;
    int   r0 = 0, r1 = 0, r2 = 0;
    const int stp = side ? 1 : -1;
    int   ptr  = side ? lo : lo - 1;
    float bnd  = 0.f;
    bool  done = false;

    // cap 260 > 2048/8: each side exhausts (bnd=INF) before the cap.
    for (int it = 0; it < 260; ++it) {
        if (!__any(!done)) break;
        if (!done) {                               // exec-masked hot body
#pragma unroll
            for (int k = 0; k < 8; ++k) {
                const int  jm  = ptr + stp * k;
                const int  rk  = jm & (M_PT - 1);
                const bool inb = (unsigned)jm < (unsigned)M_PT;
                const float4 p = pts[rk];
                float d = fmaf(p.x, qx, fmaf(p.y, qy, fmaf(p.z, qz, p.w)));
                d = inb ? d : 3.4e38f;
                const bool c0 = d < v0, c1 = d < v1, c2 = d < v2;
                const float n1v = __builtin_amdgcn_fmed3f(d, v0, v1);
                const float n2v = __builtin_amdgcn_fmed3f(d, v1, v2);
                r2 = c1 ? r1 : (c2 ? rk : r2);
                r1 = c0 ? r0 : (c1 ? rk : r1);
                r0 = c0 ? rk : r0;
                v0 = fminf(d, v0); v1 = n1v; v2 = n2v;
            }
            ptr += stp * 8;
            // frontier bound for the next unscanned point on this side
            const float fx = pts[ptr & (M_PT - 1)].x;
            float t = fmaf(0.5f, fx, qx);          // qx - x[ptr]
            t = side ? -t : t;
            t = fmaxf(t, 0.f);
            bnd = ((unsigned)ptr < (unsigned)M_PT) ? t * t : 3.4e38f;
        }
        // all lanes active at the exchange; a done partner's v2 is final
        const float v2p = __shfl_xor(v2, 1);
        const float thr = fminf(v2, v2p) + n1q + 1e-3f;
        if (!done) done = (bnd >= thr);
    }

    // merge partner's triple (sides processed disjoint point sets)
    const float m0 = __shfl_xor(v0, 1), m1 = __shfl_xor(v1, 1),
                m2 = __shfl_xor(v2, 1);
    const int   s0 = __shfl_xor(r0, 1), s1 = __shfl_xor(r1, 1),
                s2 = __shfl_xor(r2, 1);
#pragma unroll
    for (int t = 0; t < 3; ++t) {
        const float d = (t == 0) ? m0 : (t == 1) ? m1 : m2;
        const int  rk = (t == 0) ? s0 : (t == 1) ? s1 : s2;
        const bool c0 = d < v0, c1 = d < v1, c2 = d < v2;
        const float n1v = __builtin_amdgcn_fmed3f(d, v0, v1);
        const float n2v = __builtin_amdgcn_fmed3f(d, v1, v2);
        r2 = c1 ? r1 : (c2 ? rk : r2);
        r1 = c0 ? r0 : (c1 ? rk : r1);
        r0 = c0 ? rk : r0;
        v0 = fminf(d, v0); v1 = n1v; v2 = n2v;
    }

    if (side == 0) {   // weights: identical formula to the passing rounds
        const int i0 = idxs[r0], i1 = idxs[r1], i2 = idxs[r2];
        const float rr0 = 1.f / ((v0 + n1q) + 1e-8f);
        const float rr1 = 1.f / ((v1 + n1q) + 1e-8f);
        const float rr2 = 1.f / ((v2 + n1q) + 1e-8f);
        const float rs  = 1.f / (rr0 + rr1 + rr2);
        w4[qid]    = make_float4(rr0 * rs, rr1 * rs, rr2 * rs, 0.f);
        gidx4[qid] = make_int4(i0, i1, i2, 0);
    }
}

// ---------------------------------------------------------------------------
// bf16 MFMA GEMM (m97 structure), optional fused BN-stats partials.
// C stride is H_OUT=256 for all uses (Z, y2).  grid = (rows/128)*2.
// ---------------------------------------------------------------------------
template <int K, bool STATS>
__global__ __launch_bounds__(256, 2) void gemm_bt(const __bf16* __restrict__ A,
                                                  const __bf16* __restrict__ Bw,
                                                  __bf16* __restrict__ Cout,
                                                  float* __restrict__ partS,
                                                  float* __restrict__ partQ) {
    __shared__ __attribute__((aligned(16))) __bf16 As[128 * 32];
    __shared__ __attribute__((aligned(16))) __bf16 Bs[128 * 32];
    const int tid  = threadIdx.x;
    const int wave = tid >> 6, lane = tid & 63;
    const int wm = wave >> 1, wn = wave & 1;
    const int quad = lane >> 4, r16 = lane & 15;
    const int bx = blockIdx.x & 1, by = blockIdx.x >> 1;
    const int l4 = lane >> 2, lk = (lane & 3) * 8;

    f32x4 acc[4][4] = {};

    const __bf16* gA = A  + (size_t)(by * 128 + wave * 32 + l4) * K + lk;
    const __bf16* gB = Bw + (size_t)(bx * 128 + wave * 32 + l4) * K + lk;
    char* lA = (char*)As + wave * 2048;
    char* lB = (char*)Bs + wave * 2048;

    for (int k0 = 0; k0 < K; k0 += 32) {
        async_copy16(gA + k0,                  lA);
        async_copy16(gA + k0 + (size_t)16 * K, lA + 1024);
        async_copy16(gB + k0,                  lB);
        async_copy16(gB + k0 + (size_t)16 * K, lB + 1024);
        __syncthreads();

        bf16x8 af[4], bf[4];
#pragma unroll
        for (int t = 0; t < 4; ++t)
            af[t] = *(const bf16x8*)(As + (wm * 64 + t * 16 + r16) * 32 + quad * 8);
#pragma unroll
        for (int u = 0; u < 4; ++u)
            bf[u] = *(const bf16x8*)(Bs + (wn * 64 + u * 16 + r16) * 32 + quad * 8);
#pragma unroll
        for (int t = 0; t < 4; ++t)
#pragma unroll
            for (int u = 0; u < 4; ++u)
                acc[t][u] = __builtin_amdgcn_mfma_f32_16x16x32_bf16(af[t], bf[u], acc[t][u], 0, 0, 0);
        __syncthreads();
    }

    // C/D layout col=lane&15, row=(lane>>4)*4+reg [m89-verified]
#pragma unroll
    for (int t = 0; t < 4; ++t) {
#pragma unroll
        for (int u = 0; u < 4; ++u) {
            const int col = bx * 128 + wn * 64 + u * 16 + r16;
#pragma unroll
            for (int r = 0; r < 4; ++r) {
                const int row = by * 128 + wm * 64 + t * 16 + quad * 4 + r;
                Cout[(size_t)row * H_OUT + col] = (__bf16)acc[t][u][r];
            }
        }
    }

    if constexpr (STATS) {
        float* redS = (float*)As;          // [col(128)][slot(8)]
        float* redQ = ((float*)As) + 1024;
        const int slot = wm * 4 + quad;
#pragma unroll
        for (int u = 0; u < 4; ++u) {
            float s = 0.f, qq = 0.f;
#pragma unroll
            for (int t = 0; t < 4; ++t)
#pragma unroll
                for (int r = 0; r < 4; ++r) { float v = acc[t][u][r]; s += v; qq = fmaf(v, v, qq); }
            const int col = wn * 64 + u * 16 + r16;
            redS[col * 8 + slot] = s;
            redQ[col * 8 + slot] = qq;
        }
        __syncthreads();
        if (tid < 128) {
            float s = 0.f, qq = 0.f;
#pragma unroll
            for (int k = 0; k < 8; ++k) { s += redS[tid * 8 + k]; qq += redQ[tid * 8 + k]; }
            partS[(size_t)blockIdx.x * 128 + tid] = s;
            partQ[(size_t)blockIdx.x * 128 + tid] = qq;
        }
    }
}

// ---------------------------------------------------------------------------
// GEMM-A (K=128) + fused interpolation epilogue + BN-stats:
//   y1 = p1b @ wb1a^T + sum_k w_k * Z[idx_k]      (linearity of interp)
// Z rows are L2-resident (8.4 MB); gathers are 16-lane-contiguous 2B loads.
// grid = 512*2 = 1024 blocks of 256.  (idx/w come directly from knn_sweep.)
// ---------------------------------------------------------------------------
__global__ __launch_bounds__(256, 2) void gemm_a_int(
    const __bf16* __restrict__ A,  const __bf16* __restrict__ Bw,
    const __bf16* __restrict__ zb, const int4* __restrict__ gidx4,
    const float4* __restrict__ w4, __bf16* __restrict__ Cout,
    float* __restrict__ partS, float* __restrict__ partQ) {
    constexpr int K = C1;   // 128
    __shared__ __attribute__((aligned(16))) __bf16 As[128 * 32];
    __shared__ __attribute__((aligned(16))) __bf16 Bs[128 * 32];
    const int tid  = threadIdx.x;
    const int wave = tid >> 6, lane = tid & 63;
    const int wm = wave >> 1, wn = wave & 1;
    const int quad = lane >> 4, r16 = lane & 15;
    const int bx = blockIdx.x & 1, by = blockIdx.x >> 1;
    const int l4 = lane >> 2, lk = (lane & 3) * 8;

    f32x4 acc[4][4] = {};

    const __bf16* gA = A  + (size_t)(by * 128 + wave * 32 + l4) * K + lk;
    const __bf16* gB = Bw + (size_t)(bx * 128 + wave * 32 + l4) * K + lk;
    char* lA = (char*)As + wave * 2048;
    char* lB = (char*)Bs + wave * 2048;

    for (int k0 = 0; k0 < K; k0 += 32) {
        async_copy16(gA + k0,                  lA);
        async_copy16(gA + k0 + (size_t)16 * K, lA + 1024);
        async_copy16(gB + k0,                  lB);
        async_copy16(gB + k0 + (size_t)16 * K, lB + 1024);
        __syncthreads();

        bf16x8 af[4], bf[4];
#pragma unroll
        for (int t = 0; t < 4; ++t)
            af[t] = *(const bf16x8*)(As + (wm * 64 + t * 16 + r16) * 32 + quad * 8);
#pragma unroll
        for (int u = 0; u < 4; ++u)
            bf[u] = *(const bf16x8*)(Bs + (wn * 64 + u * 16 + r16) * 32 + quad * 8);
#pragma unroll
        for (int t = 0; t < 4; ++t)
#pragma unroll
            for (int u = 0; u < 4; ++u)
                acc[t][u] = __builtin_amdgcn_mfma_f32_16x16x32_bf16(af[t], bf[u], acc[t][u], 0, 0, 0);
        __syncthreads();
    }

    // stage per-row (idx0..2, w0..2) into As (4 KB of the free 8 KB)
    if (tid < 128) {
        const int q = by * 128 + tid;
        ((int4*)As)[tid * 2]       = gidx4[q];
        ((float4*)As)[tid * 2 + 1] = w4[q];
    }
    __syncthreads();

    // add interpolated Z rows into the accumulators
    const int bbase = (by >> 6) * M_PT;   // 64 row-blocks per batch
#pragma unroll
    for (int t = 0; t < 4; ++t) {
#pragma unroll
        for (int r = 0; r < 4; ++r) {
            const int rl = wm * 64 + t * 16 + quad * 4 + r;   // row-in-block
            const int4   ii = ((const int4*)As)[rl * 2];      // broadcast read
            const float4 ww = ((const float4*)As)[rl * 2 + 1];
            const __bf16* z0 = zb + (size_t)(bbase + ii.x) * H_OUT;
            const __bf16* z1 = zb + (size_t)(bbase + ii.y) * H_OUT;
            const __bf16* z2 = zb + (size_t)(bbase + ii.z) * H_OUT;
#pragma unroll
            for (int u = 0; u < 4; ++u) {
                const int col = bx * 128 + wn * 64 + u * 16 + r16;
                acc[t][u][r] += ww.x * (float)z0[col] + ww.y * (float)z1[col]
                              + ww.z * (float)z2[col];
            }
        }
    }

    // C store (bf16 y1)
#pragma unroll
    for (int t = 0; t < 4; ++t) {
#pragma unroll
        for (int u = 0; u < 4; ++u) {
            const int col = bx * 128 + wn * 64 + u * 16 + r16;
#pragma unroll
            for (int r = 0; r < 4; ++r) {
                const int row = by * 128 + wm * 64 + t * 16 + quad * 4 + r;
                Cout[(size_t)row * H_OUT + col] = (__bf16)acc[t][u][r];
            }
        }
    }

    __syncthreads();   // idx/w reads done before stats overwrite As
    float* redS = (float*)As;
    float* redQ = ((float*)As) + 1024;
    const int slot = wm * 4 + quad;
#pragma unroll
    for (int u = 0; u < 4; ++u) {
        float s = 0.f, qq = 0.f;
#pragma unroll
        for (int t = 0; t < 4; ++t)
#pragma unroll
            for (int r = 0; r < 4; ++r) { float v = acc[t][u][r]; s += v; qq = fmaf(v, v, qq); }
        const int col = wn * 64 + u * 16 + r16;
        redS[col * 8 + slot] = s;
        redQ[col * 8 + slot] = qq;
    }
    __syncthreads();
    if (tid < 128) {
        float s = 0.f, qq = 0.f;
#pragma unroll
        for (int k = 0; k < 8; ++k) { s += redS[tid * 8 + k]; qq += redQ[tid * 8 + k]; }
        partS[(size_t)blockIdx.x * 128 + tid] = s;
        partQ[(size_t)blockIdx.x * 128 + tid] = qq;
    }
}

// ---------------------------------------------------------------------------
// fold per-block partials -> per-channel scale/shift.  One block per channel.
// channel c lives in gemm-blocks bid = p*2 + (c>>7), entry (c&127); p<512.
// ---------------------------------------------------------------------------
__global__ __launch_bounds__(256) void bn_finalize(const float* __restrict__ pS,
                                                   const float* __restrict__ pQ,
                                                   const float* __restrict__ gamma,
                                                   const float* __restrict__ beta,
                                                   float* __restrict__ sc,
                                                   float* __restrict__ sh) {
    __shared__ float rs[256], rq[256];
    const int c = blockIdx.x;
    const int t = threadIdx.x;
    const int half = c >> 7, lo = c & 127;
    const size_t o1 = (size_t)(2 * t + half) * 128 + lo;
    const size_t o2 = (size_t)(2 * (t + 256) + half) * 128 + lo;
    rs[t] = pS[o1] + pS[o2];
    rq[t] = pQ[o1] + pQ[o2];
    __syncthreads();
    for (int k = 128; k > 0; k >>= 1) {
        if (t < k) { rs[t] += rs[t + k]; rq[t] += rq[t + k]; }
        __syncthreads();
    }
    if (t == 0) {
        const float inv = 1.f / (float)R_TOT;
        float mean = rs[0] * inv;
        float var  = rq[0] * inv - mean * mean;
        float a    = gamma[c] * rsqrtf(var + 1e-5f);
        sc[c] = a;
        sh[c] = beta[c] - mean * a;
    }
}

// ---------------------------------------------------------------------------
// apply BN+ReLU in place (bf16, layer-1 intermediate)
// ---------------------------------------------------------------------------
__global__ __launch_bounds__(256) void apply_bf16(__bf16* __restrict__ y,
                                                  const float* __restrict__ sc,
                                                  const float* __restrict__ sh) {
    __shared__ float scs[256], shs[256];
    scs[threadIdx.x] = sc[threadIdx.x];
    shs[threadIdx.x] = sh[threadIdx.x];
    __syncthreads();
    size_t i = ((size_t)blockIdx.x * 256 + threadIdx.x) * 8;
    int c0 = (int)(i & 255);
    bf16x8 v = *(const bf16x8*)(y + i);
#pragma unroll
    for (int e = 0; e < 8; ++e) {
        float f = fmaf((float)v[e], scs[c0 + e], shs[c0 + e]);
        v[e] = (__bf16)fmaxf(f, 0.f);
    }
    *(bf16x8*)(y + i) = v;
}

// ---------------------------------------------------------------------------
// apply BN+ReLU reading bf16 y2, writing fp32 output
// ---------------------------------------------------------------------------
__global__ __launch_bounds__(256) void apply_out(const __bf16* __restrict__ y,
                                                 const float* __restrict__ sc,
                                                 const float* __restrict__ sh,
                                                 float* __restrict__ out) {
    __shared__ float scs[256], shs[256];
    scs[threadIdx.x] = sc[threadIdx.x];
    shs[threadIdx.x] = sh[threadIdx.x];
    __syncthreads();
    size_t i = ((size_t)blockIdx.x * 256 + threadIdx.x) * 8;
    int c0 = (int)(i & 255);
    bf16x8 v = *(const bf16x8*)(y + i);
    f32x4 o0, o1;
#pragma unroll
    for (int e = 0; e < 4; ++e)
        o0[e] = fmaxf(fmaf((float)v[e], scs[c0 + e], shs[c0 + e]), 0.f);
#pragma unroll
    for (int e = 0; e < 4; ++e)
        o1[e] = fmaxf(fmaf((float)v[4 + e], scs[c0 + 4 + e], shs[c0 + 4 + e]), 0.f);
    *(f32x4*)(out + i)     = o0;
    *(f32x4*)(out + i + 4) = o1;
}

// ---------------------------------------------------------------------------
extern "C" void kernel_launch(void* const* d_in, const int* in_sizes, int n_in,
                              void* d_out, int out_size, void* d_ws, size_t ws_size,
                              hipStream_t stream) {
    const float* xyz1 = (const float*)d_in[0];
    const float* xyz2 = (const float*)d_in[1];
    const float* p1   = (const float*)d_in[2];
    const float* p2   = (const float*)d_in[3];
    const float* W1   = (const float*)d_in[4];
    // d_in[5] = b1  (cancels in batch-norm)
    const float* g1   = (const float*)d_in[6];
    const float* be1  = (const float*)d_in[7];
    const float* W2   = (const float*)d_in[8];
    // d_in[9] = b2  (cancels in batch-norm)
    const float* g2   = (const float*)d_in[10];
    const float* be2  = (const float*)d_in[11];
    float* out = (float*)d_out;

    // workspace layout (16B aligned), max ~76.9 MB:
    //   gidx4/spts/sidx/qord live in the y2b overlay region (all dead after
    //   gemm_a_int / knn_sweep, before gemm_bt<H_OUT> writes y2b)
    char* ws = (char*)d_ws;
    __bf16* y1b   = (__bf16*)(ws);                     // 33,554,432
    int4*   gidx4 = (int4*)  (ws + 33554432);          //  1,048,576
    float4* spts  = (float4*)(ws + 34603008);          //    262,144
    int*    sidx  = (int*)   (ws + 34865152);          //     65,536
    int*    qord  = (int*)   (ws + 34930688);          //    262,144
    __bf16* zb    = (__bf16*)(ws + 41943040);          //  8,388,608
    float4* w4    = (float4*)(ws + 50331648);          //  1,048,576
    __bf16* p2b   = (__bf16*)(ws + 51380224);          //  8,388,608
    __bf16* p1b   = (__bf16*)(ws + 59768832);          // 16,777,216
    __bf16* y2b   = (__bf16*)(ws + 33554432);          // 33,554,432 (overlay)
    __bf16* wb1a  = (__bf16*)(ws + 76546048);          //     65,536
    __bf16* wb1b  = (__bf16*)(ws + 76611584);          //    131,072
    __bf16* wb2   = (__bf16*)(ws + 76742656);          //    131,072
    float*  sc1   = (float*) (ws + 76873728);
    float*  sh1   = sc1 + 256;
    float*  sc2   = sc1 + 512;
    float*  sh2   = sc1 + 768;

    float* partS1 = (float*)d_out;            // d_out dead until apply_out
    float* partQ1 = partS1 + 131072;
    float* partS2 = partS1 + 262144;
    float* partQ2 = partS1 + 393216;

    convert_sort<<<2120, 256, 0, stream>>>(xyz1, xyz2, p1, p2, W1, W2,
                                           p1b, p2b, wb1a, wb1b, wb2,
                                           spts, sidx, qord);
    knn_sweep<<<512, 256, 0, stream>>>(xyz1, spts, sidx, qord, w4, gidx4);

    gemm_bt<C2, false><<<256, 256, 0, stream>>>(p2b, wb1b, zb, nullptr, nullptr);
    gemm_a_int<<<1024, 256, 0, stream>>>(p1b, wb1a, zb, gidx4, w4, y1b,
                                         partS1, partQ1);
    bn_finalize<<<256, 256, 0, stream>>>(partS1, partQ1, g1, be1, sc1, sh1);
    apply_bf16<<<8192, 256, 0, stream>>>(y1b, sc1, sh1);

    gemm_bt<H_OUT, true><<<1024, 256, 0, stream>>>(y1b, wb2, y2b, partS2, partQ2);
    bn_finalize<<<256, 256, 0, stream>>>(partS2, partQ2, g2, be2, sc2, sh2);
    apply_out<<<8192, 256, 0, stream>>>(y2b, sc2, sh2, out);
}